// Round 20
// baseline (190.413 us; speedup 1.0000x reference)
//
#include <hip/hip_runtime.h>
#include <stdint.h>

#define BB 32
#define CC 2048
#define NPIX 49
#define KPAD 64

typedef __bf16 bf16;
typedef __bf16 bf16x4 __attribute__((ext_vector_type(4)));
typedef __bf16 bf16x8 __attribute__((ext_vector_type(8)));
typedef float f32x4 __attribute__((ext_vector_type(4)));
typedef uint32_t u32x4 __attribute__((ext_vector_type(4)));
typedef long i64;
typedef long i64x2 __attribute__((ext_vector_type(2)));

#define MFMA(a,b,c) __builtin_amdgcn_mfma_f32_16x16x32_bf16(a,b,c,0,0,0)
#define MFMA8(a,b,c) __builtin_amdgcn_mfma_f32_16x16x32_fp8_fp8(a,b,c,0,0,0)
#define GLOAD_LDS(g, l) __builtin_amdgcn_global_load_lds( \
    (const __attribute__((address_space(1))) void*)(g),   \
    (__attribute__((address_space(3))) void*)(l), 16, 0, 0)

// k-interleave perm of a 4-aligned column index within its 64-block
__device__ __forceinline__ uint32_t kperm(uint32_t c) {
    uint32_t local = c & 63u, s = local >> 5, lh = (local >> 3) & 3u, o8 = local & 7u;
    return (c & ~63u) | (lh * 16u + s * 8u + o8);
}

// ---------- fused prep: x -> xb [B][C][64] AND xbT [B][64][C] ----------
__global__ void prep_fused_kernel(const float* __restrict__ x,
                                  bf16* __restrict__ xb, bf16* __restrict__ xbT) {
    __shared__ float xt[6272];   // 128*49
    const int tid = threadIdx.x;
    const int b = blockIdx.x >> 4, cb = blockIdx.x & 15;
    const float* src = x + ((size_t)(b * 2048 + cb * 128)) * 49;
#pragma unroll
    for (int i = 0; i < 25; i++) {
        int idx = i * 256 + tid;
        if (idx < 6272) xt[idx] = src[idx];
    }
    __syncthreads();
    {
        const int r = tid >> 1, h = tid & 1;
        bf16* dst = xb + ((size_t)(b * 2048 + cb * 128 + r)) * 64 + h * 32;
        const float* row = &xt[r * 49];
#pragma unroll
        for (int v = 0; v < 4; v++) {
            bf16x8 o;
#pragma unroll
            for (int e = 0; e < 8; e++) {
                int n = h * 32 + v * 8 + e;
                o[e] = (bf16)(n < 49 ? row[n] : 0.f);
            }
            *(bf16x8*)(dst + v * 8) = o;
        }
    }
    {
        const int n = tid >> 2, q = tid & 3;
        bf16* dst = xbT + ((size_t)b * 64 + n) * 2048 + cb * 128 + q * 32;
#pragma unroll
        for (int v = 0; v < 4; v++) {
            bf16x8 o;
#pragma unroll
            for (int e = 0; e < 8; e++) {
                int cl = q * 32 + v * 8 + e;
                o[e] = (bf16)(n < 49 ? xt[cl * 49 + n] : 0.f);
            }
            *(bf16x8*)(dst + v * 8) = o;
        }
    }
}

// ---------- merged: attn (bid%5==0, 512 blocks) || castw (else, 2048 blocks) ----------
// Independent work items: attn reads xb/xbT -> Ux; castw reads cw -> Uw.
// Disjoint outputs; wino_gemm launches after both complete. 1:4 interleave
// co-schedules latency-bound attn with HBM-bound castw on each CU.
__global__ __launch_bounds__(512, 2) void attn_castw_kernel(
    const bf16* __restrict__ xb, const bf16* __restrict__ xbT,
    const float* __restrict__ cw, uint8_t* __restrict__ Ux, uint8_t* __restrict__ Uw)
{
    __shared__ __align__(16) char smem[67584];
    const uint32_t bid = blockIdx.x;
    const int tid = threadIdx.x;

    if (bid % 5u != 0u) {
        // ===== castw branch: block = one co, 512 threads cover all ci =====
        uint32_t co = bid - bid / 5u - 1u;          // [0,2048)
        uint32_t q = (uint32_t)tid;                 // [0,512)
        uint32_t ci0 = q * 4u;
        uint32_t nci = kperm(ci0);
        const f32x4* src4 = (const f32x4*)(cw + ((size_t)co * 2048u + ci0) * 9u);
        float g[36];
#pragma unroll
        for (int m = 0; m < 9; m++) {
            f32x4 t4 = src4[m];
#pragma unroll
            for (int e = 0; e < 4; e++) g[m * 4 + e] = t4[e];
        }
        float u[16][4];
#pragma unroll
        for (int c4 = 0; c4 < 4; c4++) {
            const float* gg = g + c4 * 9;
            float tr[4][3];
#pragma unroll
            for (int col = 0; col < 3; col++) {
                float a0 = gg[col], a1 = gg[3 + col], a2 = gg[6 + col];
                tr[0][col] = a0;
                tr[1][col] = 0.5f * (a0 + a1 + a2);
                tr[2][col] = 0.5f * (a0 - a1 + a2);
                tr[3][col] = a2;
            }
#pragma unroll
            for (int r = 0; r < 4; r++) {
                u[r * 4 + 0][c4] = tr[r][0];
                u[r * 4 + 1][c4] = 0.5f * (tr[r][0] + tr[r][1] + tr[r][2]);
                u[r * 4 + 2][c4] = 0.5f * (tr[r][0] - tr[r][1] + tr[r][2]);
                u[r * 4 + 3][c4] = tr[r][2];
            }
        }
#pragma unroll
        for (int e = 0; e < 16; e++) {
            int p = __builtin_amdgcn_cvt_pk_fp8_f32(u[e][0] * 16.f, u[e][1] * 16.f, 0, false);
            p = __builtin_amdgcn_cvt_pk_fp8_f32(u[e][2] * 16.f, u[e][3] * 16.f, p, true);
            *(uint32_t*)(Uw + (size_t)e * 4194304u + (size_t)co * 2048u + nci) = (uint32_t)p;
        }
        return;
    }

    // ===== attn branch (R19 body, g = bid/5) =====
    bf16* Ktile = (bf16*)smem;
    bf16* Vtile = (bf16*)(smem + 16384);
    bf16 (*Plds)[16][136] = reinterpret_cast<bf16(*)[16][136]>(smem + 32768);
    bf16 (*Tlds)[132] = reinterpret_cast<bf16(*)[132]>(smem);

    const int w = tid >> 6, l = tid & 63;
    const int lhi = l >> 4, llo = l & 15;
    const uint32_t g = bid / 5u;                    // [0,512)
    const int xcd = g & 7, inner = g >> 3;
    const int b = xcd + (inner >> 4) * 8;
    const int cblk = inner & 15;
    const int c0 = cblk * 128 + w * 16;
    const bf16* xbB = xb + (size_t)b * CC * KPAD;
    const bf16* xbTB = xbT + (size_t)b * KPAD * CC;

    bf16x8 aQ[2];
#pragma unroll
    for (int kk = 0; kk < 2; kk++)
        aQ[kk] = *(const bf16x8*)(xbB + (uint32_t)(c0 + llo) * KPAD + kk * 32 + lhi * 8);

    const uint32_t rowK = tid >> 3;
    const uint32_t srcKoff = (uint32_t)(((tid & 7u) ^ (rowK & 7u)) << 3);
    const bf16* kSrc = xbB + (size_t)rowK * KPAD + srcKoff;
    const uint32_t rowV = tid >> 4;
    const uint32_t srcVoff = (uint32_t)(((tid & 15u) ^ (rowV & 7u)) << 3);
    const bf16* vSrc = xbTB + (size_t)rowV * CC + srcVoff;

    f32x4 accY[4];
#pragma unroll
    for (int nf = 0; nf < 4; nf++) accY[nf] = (f32x4){0, 0, 0, 0};
    float rowsum[4] = {};

    const float kES = -0.029442756956917622f;

    for (int dt = 0; dt < 16; dt++) {
        const int d0 = dt * 128;
#pragma unroll
        for (int i = 0; i < 2; i++) {
            GLOAD_LDS(kSrc + (size_t)(d0 + i * 64) * KPAD, (char*)Ktile + i * 8192 + tid * 16);
            GLOAD_LDS(vSrc + d0 + (size_t)i * 32 * CC,     (char*)Vtile + i * 8192 + tid * 16);
        }
        __syncthreads();

        f32x4 accS[8];
#pragma unroll
        for (int df = 0; df < 8; df++) accS[df] = (f32x4){0, 0, 0, 0};
#pragma unroll
        for (int kk = 0; kk < 2; kk++) {
#pragma unroll
            for (int df = 0; df < 8; df++) {
                uint32_t r = (uint32_t)(df * 16 + llo);
                bf16x8 bK = *(const bf16x8*)((const char*)Ktile + r * 128u +
                                             ((((uint32_t)(kk * 4 + lhi)) ^ (r & 7u)) << 4));
                accS[df] = MFMA(aQ[kk], bK, accS[df]);
            }
        }
#pragma unroll
        for (int df = 0; df < 8; df++)
#pragma unroll
            for (int r = 0; r < 4; r++) {
                float p = __builtin_amdgcn_exp2f(accS[df][r] * kES);
                rowsum[r] += p;
                Plds[w][lhi * 4 + r][df * 16 + llo] = (bf16)p;
            }
#pragma unroll
        for (int kk2 = 0; kk2 < 4; kk2++) {
            bf16x8 aP = *(const bf16x8*)&Plds[w][llo][kk2 * 32 + lhi * 8];
#pragma unroll
            for (int nf = 0; nf < 4; nf++) {
                uint32_t r = (uint32_t)(nf * 16 + llo);
                bf16x8 bV = *(const bf16x8*)((const char*)Vtile + r * 256u +
                                             ((((uint32_t)(kk2 * 4 + lhi)) ^ (r & 7u)) << 4));
                accY[nf] = MFMA(aP, bV, accY[nf]);
            }
        }
        __syncthreads();
    }
#pragma unroll
    for (int r = 0; r < 4; r++) {
        float s = rowsum[r];
        s += __shfl_xor(s, 1);
        s += __shfl_xor(s, 2);
        s += __shfl_xor(s, 4);
        s += __shfl_xor(s, 8);
        rowsum[r] = 1.0f / s;
    }
    __syncthreads();   // Tlds aliases K/V tiles
#pragma unroll
    for (int nf = 0; nf < 4; nf++)
#pragma unroll
        for (int r = 0; r < 4; r++) {
            int n = nf * 16 + llo;
            int cl = w * 16 + lhi * 4 + r;
            Tlds[n][cl] = (bf16)(accY[nf][r] * rowsum[r]);
        }
    __syncthreads();

    // ---- fused Winograd input transform ----
    {
        const int t = tid >> 5;
        const int clg = tid & 31;
        const int cl0 = clg * 4;
        const int ti = t >> 2, tj = t & 3;
        float d[4][4][4];
#pragma unroll
        for (int di = 0; di < 4; di++) {
            int i = 2 * ti + di - 1;
#pragma unroll
            for (int dj = 0; dj < 4; dj++) {
                int j = 2 * tj + dj - 1;
                if (i >= 0 && i < 7 && j >= 0 && j < 7) {
                    bf16x4 v = *(const bf16x4*)&Tlds[i * 7 + j][cl0];
#pragma unroll
                    for (int k = 0; k < 4; k++) d[di][dj][k] = (float)v[k];
                } else {
#pragma unroll
                    for (int k = 0; k < 4; k++) d[di][dj][k] = 0.f;
                }
            }
        }
        float R[4][4][4];
#pragma unroll
        for (int dj = 0; dj < 4; dj++)
#pragma unroll
            for (int k = 0; k < 4; k++) {
                R[0][dj][k] = d[0][dj][k] - d[2][dj][k];
                R[1][dj][k] = d[1][dj][k] + d[2][dj][k];
                R[2][dj][k] = d[2][dj][k] - d[1][dj][k];
                R[3][dj][k] = d[1][dj][k] - d[3][dj][k];
            }
        uint32_t nci = kperm((uint32_t)(cblk * 128 + cl0));
        uint8_t* dst = Ux + (size_t)(b * 16 + t) * 2048 + nci;
#pragma unroll
        for (int r = 0; r < 4; r++) {
            float V[4][4];
#pragma unroll
            for (int k = 0; k < 4; k++) {
                V[0][k] = (R[r][0][k] - R[r][2][k]) * 4.f;
                V[1][k] = (R[r][1][k] + R[r][2][k]) * 4.f;
                V[2][k] = (R[r][2][k] - R[r][1][k]) * 4.f;
                V[3][k] = (R[r][1][k] - R[r][3][k]) * 4.f;
            }
#pragma unroll
            for (int cc = 0; cc < 4; cc++) {
                int p = __builtin_amdgcn_cvt_pk_fp8_f32(V[cc][0], V[cc][1], 0, false);
                p = __builtin_amdgcn_cvt_pk_fp8_f32(V[cc][2], V[cc][3], p, true);
                *(uint32_t*)(dst + (size_t)(r * 4 + cc) * 1048576u) = (uint32_t)p;
            }
        }
    }
}

// ---------- Winograd GEMM fp8 (K=2048, K-tile 128): b128 frag reads ----------
#define CONV_BARRIER() do { __builtin_amdgcn_sched_barrier(0); \
    __builtin_amdgcn_s_barrier(); __builtin_amdgcn_sched_barrier(0); } while (0)
#define CONV_VMW(n) asm volatile("s_waitcnt vmcnt(" #n ")" ::: "memory")

#define WSTAGE(bufOff, t, kh) do {                                             \
    uint32_t kA_ = (uint32_t)(t) * 128u + (uint32_t)(kh) * 64u;                \
    _Pragma("unroll")                                                          \
    for (int i_ = 0; i_ < 2; i_++) {                                           \
        GLOAD_LDS(srcA[i_] + kA_,                                              \
                  smem + (bufOff) + (kh) * 16384 + i_ * 8192 + tid * 16);      \
        GLOAD_LDS(srcB[i_] + kA_,                                              \
                  smem + (bufOff) + 32768 + (kh) * 16384 + i_ * 8192 + tid * 16); \
    }                                                                          \
} while (0)

#define CONV_PHASE(bufOff, kk, GATE, STAGE_STMT) do {                          \
    CONV_VMW(GATE);                                                            \
    CONV_BARRIER();                                                            \
    i64x2 af[8], bfr[4];                                                       \
    _Pragma("unroll")                                                          \
    for (int f = 0; f < 8; f++)                                                \
        af[f] = *(const i64x2*)(smem + (bufOff) + (kk) * 16384 + offA[f]);     \
    _Pragma("unroll")                                                          \
    for (int f = 0; f < 4; f++)                                                \
        bfr[f] = *(const i64x2*)(smem + (bufOff) + 32768 + (kk) * 16384 + offB[f]); \
    STAGE_STMT;                                                                \
    asm volatile("s_waitcnt lgkmcnt(0)" ::: "memory");                         \
    __builtin_amdgcn_sched_barrier(0);                                         \
    __builtin_amdgcn_s_setprio(1);                                             \
    _Pragma("unroll")                                                          \
    for (int s = 0; s < 2; s++)                                                \
        _Pragma("unroll")                                                      \
        for (int fm = 0; fm < 8; fm++)                                         \
            _Pragma("unroll")                                                  \
            for (int fn = 0; fn < 4; fn++)                                     \
                acc[fm][fn] = MFMA8(af[fm][s], bfr[fn][s], acc[fm][fn]);       \
    __builtin_amdgcn_s_setprio(0);                                             \
    __builtin_amdgcn_sched_barrier(0);                                         \
} while (0)

__global__ __launch_bounds__(512, 2) void wino_gemm_kernel(
    const uint8_t* __restrict__ Ux, const uint8_t* __restrict__ Uw, bf16* __restrict__ Vt)
{
    extern __shared__ __align__(16) char smem[];
    const int tid = threadIdx.x;
    const int w = tid >> 6, l = tid & 63;
    const int lhi = l >> 4, llo = l & 15;
    const int wm = w >> 2, wn = w & 3;           // wave owns 128 n x 64 co

    uint32_t g = blockIdx.x;
    uint32_t xcd = g & 7u, inner = g >> 3;       // [0,32)
    uint32_t e = xcd * 2u + (inner >> 4);        // 2 e-planes per XCD
    uint32_t sub = inner & 15u;
    uint32_t mt = sub >> 3, nt = sub & 7u;

    uint32_t rowLoc = tid >> 2;                  // [0,128)
    uint32_t slot = tid & 3u;
    const uint8_t* srcA[2];
    const uint8_t* srcB[2];
#pragma unroll
    for (int i = 0; i < 2; i++) {
        uint32_t row = (uint32_t)i * 128u + rowLoc;
        uint32_t swz = (uint32_t)((slot ^ ((row >> 1) & 3u)) << 4);   // bytes
        srcA[i] = Ux + (size_t)e * 1048576u + (size_t)(mt * 256u + row) * 2048u + swz;
        srcB[i] = Uw + (size_t)e * 4194304u + (size_t)(nt * 256u + row) * 2048u + swz;
    }

    uint32_t offA[8], offB[4];
#pragma unroll
    for (int f = 0; f < 8; f++) {
        uint32_t r = (uint32_t)(wm * 128 + f * 16 + llo);
        offA[f] = r * 64u + (uint32_t)(((uint32_t)lhi ^ ((r >> 1) & 3u)) << 4);
    }
#pragma unroll
    for (int f = 0; f < 4; f++) {
        uint32_t r = (uint32_t)(wn * 64 + f * 16 + llo);
        offB[f] = r * 64u + (uint32_t)(((uint32_t)lhi ^ ((r >> 1) & 3u)) << 4);
    }

    f32x4 acc[8][4];
#pragma unroll
    for (int fm = 0; fm < 8; fm++)
#pragma unroll
        for (int fn = 0; fn < 4; fn++) acc[fm][fn] = (f32x4){0, 0, 0, 0};

    WSTAGE(0, 0, 0);
    WSTAGE(0, 0, 1);
    WSTAGE(65536, 1, 0);

    for (int it = 0; it < 7; ++it) {
        const int t0 = it * 2;
        CONV_PHASE(0,     0, 8, WSTAGE(65536, t0 + 1, 1));
        CONV_PHASE(0,     1, 8, WSTAGE(0,     t0 + 2, 0));
        CONV_PHASE(65536, 0, 8, WSTAGE(0,     t0 + 2, 1));
        CONV_PHASE(65536, 1, 8, WSTAGE(65536, t0 + 3, 0));
    }
    CONV_PHASE(0,     0, 8, WSTAGE(65536, 15, 1));
    CONV_PHASE(0,     1, 8, (void)0);
    CONV_PHASE(65536, 0, 4, (void)0);
    CONV_PHASE(65536, 1, 0, (void)0);

    bf16* pz = Vt + (size_t)e * 1048576u;
    uint32_t n0 = mt * 256u + (uint32_t)(wm * 128 + lhi * 4);
    uint32_t co0 = nt * 256u + (uint32_t)(wn * 64 + llo);
#pragma unroll
    for (int fm = 0; fm < 8; fm++)
#pragma unroll
        for (int fn = 0; fn < 4; fn++)
#pragma unroll
            for (int r = 0; r < 4; r++)
                pz[(size_t)(n0 + fm * 16u + r) * 2048u + (co0 + fn * 16u)] =
                    (bf16)acc[fm][fn][r];
}

// ---------- Winograd output transform + bias + residual (M scaled by 1/64) ----------
__global__ void wino_out_kernel(const bf16* __restrict__ Vt, const float* __restrict__ x,
                                const float* __restrict__ cb, float* __restrict__ out)
{
    __shared__ float Ml[16][16][33];
    __shared__ float Ol[32][50];
    __shared__ float cbl[32];
    const int tid = threadIdx.x;
    const int b = blockIdx.x >> 6, cg = blockIdx.x & 63;
    const int c0 = cg * 32;

    {
        int e = tid >> 4, t = tid & 15;
        const bf16* src = Vt + ((size_t)e * 512 + b * 16 + t) * 2048 + c0;
#pragma unroll
        for (int v = 0; v < 4; v++) {
            bf16x8 vv = *(const bf16x8*)(src + v * 8);
#pragma unroll
            for (int k = 0; k < 8; k++) Ml[e][t][v * 8 + k] = (float)vv[k] * 0.015625f;
        }
    }
    if (tid < 32) cbl[tid] = cb[c0 + tid];
    __syncthreads();

    {
        int t = tid & 15, cp = tid >> 4;
        int ti = t >> 2, tj = t & 3;
#pragma unroll
        for (int cc2 = 0; cc2 < 2; cc2++) {
            int cc = cp * 2 + cc2;
            float M[16];
#pragma unroll
            for (int e = 0; e < 16; e++) M[e] = Ml[e][t][cc];
            float s0[4], s1[4];
#pragma unroll
            for (int col = 0; col < 4; col++) {
                s0[col] = M[col] + M[4 + col] + M[8 + col];
                s1[col] = M[4 + col] - M[8 + col] - M[12 + col];
            }
            float y00 = s0[0] + s0[1] + s0[2];
            float y01 = s0[1] - s0[2] - s0[3];
            float y10 = s1[0] + s1[1] + s1[2];
            float y11 = s1[1] - s1[2] - s1[3];
            int i0 = 2 * ti, j0 = 2 * tj;
            Ol[cc][i0 * 7 + j0] = y00;
            if (j0 + 1 < 7) Ol[cc][i0 * 7 + j0 + 1] = y01;
            if (i0 + 1 < 7) Ol[cc][(i0 + 1) * 7 + j0] = y10;
            if (i0 + 1 < 7 && j0 + 1 < 7) Ol[cc][(i0 + 1) * 7 + j0 + 1] = y11;
        }
    }
    __syncthreads();

    {
        const float* xs = x + ((size_t)b * 2048 + c0) * 49;
        float* os = out + ((size_t)b * 2048 + c0) * 49;
        for (int k = tid; k < 1568; k += 256) {
            int c = k / 49, p = k - c * 49;
            os[k] = Ol[c][p] + cbl[c] + xs[k];
        }
    }
}

extern "C" void kernel_launch(void* const* d_in, const int* in_sizes, int n_in,
                              void* d_out, int out_size, void* d_ws, size_t ws_size,
                              hipStream_t stream) {
    (void)in_sizes; (void)n_in; (void)out_size; (void)ws_size;
    const float* x = (const float*)d_in[0];
    const float* cw = (const float*)d_in[1];
    const float* cb = (const float*)d_in[2];
    float* out = (float*)d_out;
    char* ws = (char*)d_ws;

    // layout (peak 134.2 MB):
    bf16* xb     = (bf16*)(ws);
    bf16* xbT    = (bf16*)(ws + 8388608);
    uint8_t* Ux  = (uint8_t*)(ws + 16777216);
    uint8_t* Uw  = (uint8_t*)(ws + 33554432);
    bf16* Vt     = (bf16*)(ws + 100663296);

    hipFuncSetAttribute((const void*)wino_gemm_kernel,
                        hipFuncAttributeMaxDynamicSharedMemorySize, 131072);

    prep_fused_kernel<<<512, 256, 0, stream>>>(x, xb, xbT);
    attn_castw_kernel<<<2560, 512, 0, stream>>>(xb, xbT, cw, Ux, Uw);
    wino_gemm_kernel<<<256, 512, 131072, stream>>>(Ux, Uw, Vt);
    wino_out_kernel<<<2048, 256, 0, stream>>>(Vt, x, cb, out);
}

// Round 21
// 184.938 us; speedup vs baseline: 1.0296x; 1.0296x over previous
//
#include <hip/hip_runtime.h>
#include <stdint.h>

#define BB 32
#define CC 2048
#define NPIX 49
#define KPAD 64

typedef __bf16 bf16;
typedef __bf16 bf16x4 __attribute__((ext_vector_type(4)));
typedef __bf16 bf16x8 __attribute__((ext_vector_type(8)));
typedef float f32x4 __attribute__((ext_vector_type(4)));
typedef uint32_t u32x4 __attribute__((ext_vector_type(4)));
typedef long i64;
typedef long i64x2 __attribute__((ext_vector_type(2)));

#define MFMA(a,b,c) __builtin_amdgcn_mfma_f32_16x16x32_bf16(a,b,c,0,0,0)
#define MFMA8(a,b,c) __builtin_amdgcn_mfma_f32_16x16x32_fp8_fp8(a,b,c,0,0,0)
#define GLOAD_LDS(g, l) __builtin_amdgcn_global_load_lds( \
    (const __attribute__((address_space(1))) void*)(g),   \
    (__attribute__((address_space(3))) void*)(l), 16, 0, 0)

// k-interleave perm of a 4-aligned column index within its 64-block:
// newlocal = lhi*16 + s*8 + (local&7)  (lane lhi's two 8B k-step chunks adjacent)
__device__ __forceinline__ uint32_t kperm(uint32_t c) {
    uint32_t local = c & 63u, s = local >> 5, lh = (local >> 3) & 3u, o8 = local & 7u;
    return (c & ~63u) | (lh * 16u + s * 8u + o8);
}

// ---------- fused prep: x -> xb [B][C][64] AND xbT [B][64][C] ----------
__global__ void prep_fused_kernel(const float* __restrict__ x,
                                  bf16* __restrict__ xb, bf16* __restrict__ xbT) {
    __shared__ float xt[6272];   // 128*49
    const int tid = threadIdx.x;
    const int b = blockIdx.x >> 4, cb = blockIdx.x & 15;
    const float* src = x + ((size_t)(b * 2048 + cb * 128)) * 49;
#pragma unroll
    for (int i = 0; i < 25; i++) {
        int idx = i * 256 + tid;
        if (idx < 6272) xt[idx] = src[idx];
    }
    __syncthreads();
    {
        const int r = tid >> 1, h = tid & 1;
        bf16* dst = xb + ((size_t)(b * 2048 + cb * 128 + r)) * 64 + h * 32;
        const float* row = &xt[r * 49];
#pragma unroll
        for (int v = 0; v < 4; v++) {
            bf16x8 o;
#pragma unroll
            for (int e = 0; e < 8; e++) {
                int n = h * 32 + v * 8 + e;
                o[e] = (bf16)(n < 49 ? row[n] : 0.f);
            }
            *(bf16x8*)(dst + v * 8) = o;
        }
    }
    {
        const int n = tid >> 2, q = tid & 3;
        bf16* dst = xbT + ((size_t)b * 64 + n) * 2048 + cb * 128 + q * 32;
#pragma unroll
        for (int v = 0; v < 4; v++) {
            bf16x8 o;
#pragma unroll
            for (int e = 0; e < 8; e++) {
                int cl = q * 32 + v * 8 + e;
                o[e] = (bf16)(n < 49 ? xt[cl * 49 + n] : 0.f);
            }
            *(bf16x8*)(dst + v * 8) = o;
        }
    }
}

// ---------- Winograd weight transform -> Uw fp8 e4m3 [16][co][kperm(ci)], x16 ----------
__global__ void castw_wino_kernel(const float* __restrict__ cw, uint8_t* __restrict__ Uw) {
    uint32_t t = blockIdx.x * 256u + threadIdx.x;   // 2048*512
    uint32_t q = t & 511u, co = t >> 9;
    uint32_t ci0 = q * 4u;
    uint32_t nci = kperm(ci0);
    const f32x4* src4 = (const f32x4*)(cw + ((size_t)co * 2048u + ci0) * 9u);
    float g[36];
#pragma unroll
    for (int m = 0; m < 9; m++) {
        f32x4 t4 = src4[m];
#pragma unroll
        for (int e = 0; e < 4; e++) g[m * 4 + e] = t4[e];
    }
    float u[16][4];
#pragma unroll
    for (int c4 = 0; c4 < 4; c4++) {
        const float* gg = g + c4 * 9;
        float tr[4][3];
#pragma unroll
        for (int col = 0; col < 3; col++) {
            float a0 = gg[col], a1 = gg[3 + col], a2 = gg[6 + col];
            tr[0][col] = a0;
            tr[1][col] = 0.5f * (a0 + a1 + a2);
            tr[2][col] = 0.5f * (a0 - a1 + a2);
            tr[3][col] = a2;
        }
#pragma unroll
        for (int r = 0; r < 4; r++) {
            u[r * 4 + 0][c4] = tr[r][0];
            u[r * 4 + 1][c4] = 0.5f * (tr[r][0] + tr[r][1] + tr[r][2]);
            u[r * 4 + 2][c4] = 0.5f * (tr[r][0] - tr[r][1] + tr[r][2]);
            u[r * 4 + 3][c4] = tr[r][2];
        }
    }
#pragma unroll
    for (int e = 0; e < 16; e++) {
        int p = __builtin_amdgcn_cvt_pk_fp8_f32(u[e][0] * 16.f, u[e][1] * 16.f, 0, false);
        p = __builtin_amdgcn_cvt_pk_fp8_f32(u[e][2] * 16.f, u[e][3] * 16.f, p, true);
        *(uint32_t*)(Uw + (size_t)e * 4194304u + (size_t)co * 2048u + nci) = (uint32_t)p;
    }
}

// ---------- fused bilinear -> softmax -> Y -> Winograd-in (B^T d B) -> Ux fp8 ----------
__global__ __launch_bounds__(512, 2) void attn_kernel(
    const bf16* __restrict__ xb, const bf16* __restrict__ xbT, uint8_t* __restrict__ Ux)
{
    __shared__ __align__(16) char smem[67584];
    bf16* Ktile = (bf16*)smem;
    bf16* Vtile = (bf16*)(smem + 16384);
    bf16 (*Plds)[16][136] = reinterpret_cast<bf16(*)[16][136]>(smem + 32768);
    bf16 (*Tlds)[132] = reinterpret_cast<bf16(*)[132]>(smem);

    const int tid = threadIdx.x;
    const int w = tid >> 6, l = tid & 63;
    const int lhi = l >> 4, llo = l & 15;
    const uint32_t g = blockIdx.x;
    const int xcd = g & 7, inner = g >> 3;
    const int b = xcd + (inner >> 4) * 8;
    const int cblk = inner & 15;
    const int c0 = cblk * 128 + w * 16;
    const bf16* xbB = xb + (size_t)b * CC * KPAD;
    const bf16* xbTB = xbT + (size_t)b * KPAD * CC;

    bf16x8 aQ[2];
#pragma unroll
    for (int kk = 0; kk < 2; kk++)
        aQ[kk] = *(const bf16x8*)(xbB + (uint32_t)(c0 + llo) * KPAD + kk * 32 + lhi * 8);

    const uint32_t rowK = tid >> 3;
    const uint32_t srcKoff = (uint32_t)(((tid & 7u) ^ (rowK & 7u)) << 3);
    const bf16* kSrc = xbB + (size_t)rowK * KPAD + srcKoff;
    const uint32_t rowV = tid >> 4;
    const uint32_t srcVoff = (uint32_t)(((tid & 15u) ^ (rowV & 7u)) << 3);
    const bf16* vSrc = xbTB + (size_t)rowV * CC + srcVoff;

    f32x4 accY[4];
#pragma unroll
    for (int nf = 0; nf < 4; nf++) accY[nf] = (f32x4){0, 0, 0, 0};
    float rowsum[4] = {};

    const float kES = -0.029442756956917622f;

    for (int dt = 0; dt < 16; dt++) {
        const int d0 = dt * 128;
#pragma unroll
        for (int i = 0; i < 2; i++) {
            GLOAD_LDS(kSrc + (size_t)(d0 + i * 64) * KPAD, (char*)Ktile + i * 8192 + tid * 16);
            GLOAD_LDS(vSrc + d0 + (size_t)i * 32 * CC,     (char*)Vtile + i * 8192 + tid * 16);
        }
        __syncthreads();

        f32x4 accS[8];
#pragma unroll
        for (int df = 0; df < 8; df++) accS[df] = (f32x4){0, 0, 0, 0};
#pragma unroll
        for (int kk = 0; kk < 2; kk++) {
#pragma unroll
            for (int df = 0; df < 8; df++) {
                uint32_t r = (uint32_t)(df * 16 + llo);
                bf16x8 bK = *(const bf16x8*)((const char*)Ktile + r * 128u +
                                             ((((uint32_t)(kk * 4 + lhi)) ^ (r & 7u)) << 4));
                accS[df] = MFMA(aQ[kk], bK, accS[df]);
            }
        }
#pragma unroll
        for (int df = 0; df < 8; df++)
#pragma unroll
            for (int r = 0; r < 4; r++) {
                float p = __builtin_amdgcn_exp2f(accS[df][r] * kES);
                rowsum[r] += p;
                Plds[w][lhi * 4 + r][df * 16 + llo] = (bf16)p;
            }
#pragma unroll
        for (int kk2 = 0; kk2 < 4; kk2++) {
            bf16x8 aP = *(const bf16x8*)&Plds[w][llo][kk2 * 32 + lhi * 8];
#pragma unroll
            for (int nf = 0; nf < 4; nf++) {
                uint32_t r = (uint32_t)(nf * 16 + llo);
                bf16x8 bV = *(const bf16x8*)((const char*)Vtile + r * 256u +
                                             ((((uint32_t)(kk2 * 4 + lhi)) ^ (r & 7u)) << 4));
                accY[nf] = MFMA(aP, bV, accY[nf]);
            }
        }
        __syncthreads();
    }
#pragma unroll
    for (int r = 0; r < 4; r++) {
        float s = rowsum[r];
        s += __shfl_xor(s, 1);
        s += __shfl_xor(s, 2);
        s += __shfl_xor(s, 4);
        s += __shfl_xor(s, 8);
        rowsum[r] = 1.0f / s;
    }
    __syncthreads();   // Tlds aliases K/V tiles
#pragma unroll
    for (int nf = 0; nf < 4; nf++)
#pragma unroll
        for (int r = 0; r < 4; r++) {
            int n = nf * 16 + llo;
            int cl = w * 16 + lhi * 4 + r;
            Tlds[n][cl] = (bf16)(accY[nf][r] * rowsum[r]);
        }
    __syncthreads();

    // ---- fused Winograd input transform: per (tile t, 4-col group) ----
    {
        const int t = tid >> 5;                // 16 tiles
        const int clg = tid & 31;              // 32 col-groups of 4
        const int cl0 = clg * 4;
        const int ti = t >> 2, tj = t & 3;
        float d[4][4][4];
#pragma unroll
        for (int di = 0; di < 4; di++) {
            int i = 2 * ti + di - 1;
#pragma unroll
            for (int dj = 0; dj < 4; dj++) {
                int j = 2 * tj + dj - 1;
                if (i >= 0 && i < 7 && j >= 0 && j < 7) {
                    bf16x4 v = *(const bf16x4*)&Tlds[i * 7 + j][cl0];
#pragma unroll
                    for (int k = 0; k < 4; k++) d[di][dj][k] = (float)v[k];
                } else {
#pragma unroll
                    for (int k = 0; k < 4; k++) d[di][dj][k] = 0.f;
                }
            }
        }
        float R[4][4][4];
#pragma unroll
        for (int dj = 0; dj < 4; dj++)
#pragma unroll
            for (int k = 0; k < 4; k++) {
                R[0][dj][k] = d[0][dj][k] - d[2][dj][k];
                R[1][dj][k] = d[1][dj][k] + d[2][dj][k];
                R[2][dj][k] = d[2][dj][k] - d[1][dj][k];
                R[3][dj][k] = d[1][dj][k] - d[3][dj][k];
            }
        uint32_t nci = kperm((uint32_t)(cblk * 128 + cl0));
        uint8_t* dst = Ux + (size_t)(b * 16 + t) * 2048 + nci;
#pragma unroll
        for (int r = 0; r < 4; r++) {
            float V[4][4];
#pragma unroll
            for (int k = 0; k < 4; k++) {
                V[0][k] = (R[r][0][k] - R[r][2][k]) * 4.f;
                V[1][k] = (R[r][1][k] + R[r][2][k]) * 4.f;
                V[2][k] = (R[r][2][k] - R[r][1][k]) * 4.f;
                V[3][k] = (R[r][1][k] - R[r][3][k]) * 4.f;
            }
#pragma unroll
            for (int cc = 0; cc < 4; cc++) {
                int p = __builtin_amdgcn_cvt_pk_fp8_f32(V[cc][0], V[cc][1], 0, false);
                p = __builtin_amdgcn_cvt_pk_fp8_f32(V[cc][2], V[cc][3], p, true);
                *(uint32_t*)(dst + (size_t)(r * 4 + cc) * 1048576u) = (uint32_t)p;
            }
        }
    }
}

// ---------- Winograd GEMM fp8 (K=2048, K-tile 128): b128 frag reads, R14 offsets ----------
#define CONV_BARRIER() do { __builtin_amdgcn_sched_barrier(0); \
    __builtin_amdgcn_s_barrier(); __builtin_amdgcn_sched_barrier(0); } while (0)
#define CONV_VMW(n) asm volatile("s_waitcnt vmcnt(" #n ")" ::: "memory")

#define WSTAGE(bufOff, t, kh) do {                                             \
    uint32_t kA_ = (uint32_t)(t) * 128u + (uint32_t)(kh) * 64u;                \
    _Pragma("unroll")                                                          \
    for (int i_ = 0; i_ < 2; i_++) {                                           \
        GLOAD_LDS(srcA[i_] + kA_,                                              \
                  smem + (bufOff) + (kh) * 16384 + i_ * 8192 + tid * 16);      \
        GLOAD_LDS(srcB[i_] + kA_,                                              \
                  smem + (bufOff) + 32768 + (kh) * 16384 + i_ * 8192 + tid * 16); \
    }                                                                          \
} while (0)

#define CONV_PHASE(bufOff, kk, GATE, STAGE_STMT) do {                          \
    CONV_VMW(GATE);                                                            \
    CONV_BARRIER();                                                            \
    i64x2 af[8], bfr[4];                                                       \
    _Pragma("unroll")                                                          \
    for (int f = 0; f < 8; f++)                                                \
        af[f] = *(const i64x2*)(smem + (bufOff) + (kk) * 16384 + offA[f]);     \
    _Pragma("unroll")                                                          \
    for (int f = 0; f < 4; f++)                                                \
        bfr[f] = *(const i64x2*)(smem + (bufOff) + 32768 + (kk) * 16384 + offB[f]); \
    STAGE_STMT;                                                                \
    asm volatile("s_waitcnt lgkmcnt(0)" ::: "memory");                         \
    __builtin_amdgcn_sched_barrier(0);                                         \
    __builtin_amdgcn_s_setprio(1);                                             \
    _Pragma("unroll")                                                          \
    for (int s = 0; s < 2; s++)                                                \
        _Pragma("unroll")                                                      \
        for (int fm = 0; fm < 8; fm++)                                         \
            _Pragma("unroll")                                                  \
            for (int fn = 0; fn < 4; fn++)                                     \
                acc[fm][fn] = MFMA8(af[fm][s], bfr[fn][s], acc[fm][fn]);       \
    __builtin_amdgcn_s_setprio(0);                                             \
    __builtin_amdgcn_sched_barrier(0);                                         \
} while (0)

__global__ __launch_bounds__(512, 2) void wino_gemm_kernel(
    const uint8_t* __restrict__ Ux, const uint8_t* __restrict__ Uw, bf16* __restrict__ Vt)
{
    extern __shared__ __align__(16) char smem[];
    const int tid = threadIdx.x;
    const int w = tid >> 6, l = tid & 63;
    const int lhi = l >> 4, llo = l & 15;
    const int wm = w >> 2, wn = w & 3;           // wave owns 128 n x 64 co

    uint32_t g = blockIdx.x;
    uint32_t xcd = g & 7u, inner = g >> 3;       // [0,32)
    uint32_t e = xcd * 2u + (inner >> 4);        // 2 e-planes per XCD
    uint32_t sub = inner & 15u;
    uint32_t mt = sub >> 3, nt = sub & 7u;

    uint32_t rowLoc = tid >> 2;                  // [0,128)
    uint32_t slot = tid & 3u;
    const uint8_t* srcA[2];
    const uint8_t* srcB[2];
#pragma unroll
    for (int i = 0; i < 2; i++) {
        uint32_t row = (uint32_t)i * 128u + rowLoc;
        uint32_t swz = (uint32_t)((slot ^ ((row >> 1) & 3u)) << 4);   // bytes
        srcA[i] = Ux + (size_t)e * 1048576u + (size_t)(mt * 256u + row) * 2048u + swz;
        srcB[i] = Uw + (size_t)e * 4194304u + (size_t)(nt * 256u + row) * 2048u + swz;
    }

    // b128 frag offsets (k-interleaved layout makes 16B = both k-steps)
    uint32_t offA[8], offB[4];
#pragma unroll
    for (int f = 0; f < 8; f++) {
        uint32_t r = (uint32_t)(wm * 128 + f * 16 + llo);
        offA[f] = r * 64u + (uint32_t)(((uint32_t)lhi ^ ((r >> 1) & 3u)) << 4);
    }
#pragma unroll
    for (int f = 0; f < 4; f++) {
        uint32_t r = (uint32_t)(wn * 64 + f * 16 + llo);
        offB[f] = r * 64u + (uint32_t)(((uint32_t)lhi ^ ((r >> 1) & 3u)) << 4);
    }

    f32x4 acc[8][4];
#pragma unroll
    for (int fm = 0; fm < 8; fm++)
#pragma unroll
        for (int fn = 0; fn < 4; fn++) acc[fm][fn] = (f32x4){0, 0, 0, 0};

    // prologue: T0.k0, T0.k1 -> buf0; T1.k0 -> buf1
    WSTAGE(0, 0, 0);
    WSTAGE(0, 0, 1);
    WSTAGE(65536, 1, 0);

    for (int it = 0; it < 7; ++it) {
        const int t0 = it * 2;
        CONV_PHASE(0,     0, 8, WSTAGE(65536, t0 + 1, 1));
        CONV_PHASE(0,     1, 8, WSTAGE(0,     t0 + 2, 0));
        CONV_PHASE(65536, 0, 8, WSTAGE(0,     t0 + 2, 1));
        CONV_PHASE(65536, 1, 8, WSTAGE(65536, t0 + 3, 0));
    }
    // peeled final pair (tiles 14 buf0, 15 buf1); gates 8,8,4,0
    CONV_PHASE(0,     0, 8, WSTAGE(65536, 15, 1));
    CONV_PHASE(0,     1, 8, (void)0);
    CONV_PHASE(65536, 0, 4, (void)0);
    CONV_PHASE(65536, 1, 0, (void)0);

    bf16* pz = Vt + (size_t)e * 1048576u;
    uint32_t n0 = mt * 256u + (uint32_t)(wm * 128 + lhi * 4);
    uint32_t co0 = nt * 256u + (uint32_t)(wn * 64 + llo);
#pragma unroll
    for (int fm = 0; fm < 8; fm++)
#pragma unroll
        for (int fn = 0; fn < 4; fn++)
#pragma unroll
            for (int r = 0; r < 4; r++)
                pz[(size_t)(n0 + fm * 16u + r) * 2048u + (co0 + fn * 16u)] =
                    (bf16)acc[fm][fn][r];
}

// ---------- Winograd output transform + bias + residual (M scaled by 1/64) ----------
__global__ void wino_out_kernel(const bf16* __restrict__ Vt, const float* __restrict__ x,
                                const float* __restrict__ cb, float* __restrict__ out)
{
    __shared__ float Ml[16][16][33];
    __shared__ float Ol[32][50];
    __shared__ float cbl[32];
    const int tid = threadIdx.x;
    const int b = blockIdx.x >> 6, cg = blockIdx.x & 63;
    const int c0 = cg * 32;

    {
        int e = tid >> 4, t = tid & 15;
        const bf16* src = Vt + ((size_t)e * 512 + b * 16 + t) * 2048 + c0;
#pragma unroll
        for (int v = 0; v < 4; v++) {
            bf16x8 vv = *(const bf16x8*)(src + v * 8);
#pragma unroll
            for (int k = 0; k < 8; k++) Ml[e][t][v * 8 + k] = (float)vv[k] * 0.015625f;
        }
    }
    if (tid < 32) cbl[tid] = cb[c0 + tid];
    __syncthreads();

    {
        int t = tid & 15, cp = tid >> 4;
        int ti = t >> 2, tj = t & 3;
#pragma unroll
        for (int cc2 = 0; cc2 < 2; cc2++) {
            int cc = cp * 2 + cc2;
            float M[16];
#pragma unroll
            for (int e = 0; e < 16; e++) M[e] = Ml[e][t][cc];
            float s0[4], s1[4];
#pragma unroll
            for (int col = 0; col < 4; col++) {
                s0[col] = M[col] + M[4 + col] + M[8 + col];
                s1[col] = M[4 + col] - M[8 + col] - M[12 + col];
            }
            float y00 = s0[0] + s0[1] + s0[2];
            float y01 = s0[1] - s0[2] - s0[3];
            float y10 = s1[0] + s1[1] + s1[2];
            float y11 = s1[1] - s1[2] - s1[3];
            int i0 = 2 * ti, j0 = 2 * tj;
            Ol[cc][i0 * 7 + j0] = y00;
            if (j0 + 1 < 7) Ol[cc][i0 * 7 + j0 + 1] = y01;
            if (i0 + 1 < 7) Ol[cc][(i0 + 1) * 7 + j0] = y10;
            if (i0 + 1 < 7 && j0 + 1 < 7) Ol[cc][(i0 + 1) * 7 + j0 + 1] = y11;
        }
    }
    __syncthreads();

    {
        const float* xs = x + ((size_t)b * 2048 + c0) * 49;
        float* os = out + ((size_t)b * 2048 + c0) * 49;
        for (int k = tid; k < 1568; k += 256) {
            int c = k / 49, p = k - c * 49;
            os[k] = Ol[c][p] + cbl[c] + xs[k];
        }
    }
}

extern "C" void kernel_launch(void* const* d_in, const int* in_sizes, int n_in,
                              void* d_out, int out_size, void* d_ws, size_t ws_size,
                              hipStream_t stream) {
    (void)in_sizes; (void)n_in; (void)out_size; (void)ws_size;
    const float* x = (const float*)d_in[0];
    const float* cw = (const float*)d_in[1];
    const float* cb = (const float*)d_in[2];
    float* out = (float*)d_out;
    char* ws = (char*)d_ws;

    // layout (peak 134.2 MB):
    // [0]         xb  8,388,608
    // [8388608]   xbT 8,388,608
    // [16777216]  Ux fp8 16,777,216
    // [33554432]  Uw fp8 67,108,864
    // [100663296] Vt bf16 33,554,432  -> end 134,217,728
    bf16* xb     = (bf16*)(ws);
    bf16* xbT    = (bf16*)(ws + 8388608);
    uint8_t* Ux  = (uint8_t*)(ws + 16777216);
    uint8_t* Uw  = (uint8_t*)(ws + 33554432);
    bf16* Vt     = (bf16*)(ws + 100663296);

    hipFuncSetAttribute((const void*)wino_gemm_kernel,
                        hipFuncAttributeMaxDynamicSharedMemorySize, 131072);

    prep_fused_kernel<<<512, 256, 0, stream>>>(x, xb, xbT);
    castw_wino_kernel<<<4096, 256, 0, stream>>>(cw, Uw);
    attn_kernel<<<512, 512, 0, stream>>>(xb, xbT, Ux);
    wino_gemm_kernel<<<256, 512, 131072, stream>>>(Ux, Uw, Vt);
    wino_out_kernel<<<2048, 256, 0, stream>>>(Vt, x, cb, out);
}